// Round 7
// baseline (66.783 us; speedup 1.0000x reference)
//
#include <hip/hip_runtime.h>
#include <cstdint>
#include <cstddef>

#define Bb 128
#define Cc 64
#define Dd 365
#define Tt 364
#define Ss 32
#define SM1 31
#define NIJ 961
#define BASISF 1e-10f

typedef _Float16 f16x8 __attribute__((ext_vector_type(8)));
typedef float f32x4 __attribute__((ext_vector_type(4)));

// ---------------------------------------------------------------------------
// Prep: permuted+padded Bt[1024][64] f16 and emu_perm[1024] = exp(-mu) f32.
// MFMA col m <-> (i,j):  nq=m>>8, rem=m&255, qp=rem>>6, p=(rem>>4)&3, v=rem&15;
// i = nq*8 + qp*2 + (v>>3);  j = 4*(v&7) + p.
// Lane je of frag (qp,p) holds (i = base+ (je>>3), j = 4*(je&7)+p): each lane
// owns 4 CONSECUTIVE j of one i-row across the 4 p-frags -> dwordx4 stores.
// ---------------------------------------------------------------------------
__global__ void prep_kernel(const float* __restrict__ mu,
                            const float* __restrict__ beta,
                            _Float16* __restrict__ Bt,
                            float* __restrict__ emu_perm) {
    int idx = blockIdx.x * blockDim.x + threadIdx.x;   // 0 .. 65535
    int m = idx >> 6, c = idx & 63;
    int nq = m >> 8, rem = m & 255, qp = rem >> 6, p = (rem >> 4) & 3, v = rem & 15;
    int i = nq * 8 + qp * 2 + (v >> 3);
    int j = 4 * (v & 7) + p;
    float val = (i < SM1 && j < SM1) ? beta[c * NIJ + i * SM1 + j] : 0.0f;
    Bt[(size_t)m * Cc + c] = (_Float16)val;
    if (idx < 1024) {
        int m2 = idx;
        int nq2 = m2 >> 8, rem2 = m2 & 255, qp2 = rem2 >> 6;
        int p2 = (rem2 >> 4) & 3, v2 = rem2 & 15;
        int i2 = nq2 * 8 + qp2 * 2 + (v2 >> 3);
        int j2 = 4 * (v2 & 7) + p2;
        emu_perm[m2] = (i2 < SM1 && j2 < SM1) ? __expf(-mu[i2 * SM1 + j2]) : 1.0f;
    }
}

// ---- DPP helpers (pure VALU cross-lane; no DS pipe) ----
template <int CTRL>
__device__ __forceinline__ float dpp_mov(float x) {
    union { float f; int i; } u, v;
    u.f = x;
    v.i = __builtin_amdgcn_update_dpp(0, u.i, CTRL, 0xf, 0xf, true);
    return v.f;
}
template <int CTRL>
__device__ __forceinline__ float dpp_add(float s) { return s + dpp_mov<CTRL>(s); }
// quad_perm xor1 = [1,0,3,2] = 0xB1 ; xor2 = [2,3,0,1] = 0x4E
// row_ror:4 = 0x124 (dest n <- src n-4) ; row_ror:12 = 0x12C (dest n <- src n+4)
// row_shr:1 = 0x111 (dest n <- src n-1; HW-verified in rounds 2-5)

// ---------------------------------------------------------------------------
// Main kernel: 256 threads = 4 waves; block = 16 bt-rows x 1024 cols.
// Wave nq owns cols nq*256..+255 = i-rows nq*8..+7 as 4 i-pairs (qp).
// Per qp: 8 B-frag loads, 8 MFMAs, in-register epilogue, 4 dwordx4 stores.
// TLP (16 waves/CU) hides latency; normal cached stores (L2 absorbs).
// ---------------------------------------------------------------------------
__global__ __launch_bounds__(256, 4)
void transition_mfma_kernel(const float* __restrict__ adstock,
                            const _Float16* __restrict__ Bt,
                            const float* __restrict__ emu_perm,
                            float* __restrict__ out)
{
    const int bt0 = blockIdx.x * 16;
    const int tid = threadIdx.x;
    const int lane = tid & 63;
    const int nq  = tid >> 6;          // wave 0..3
    const int je  = lane & 15;
    const int grp = lane >> 4;
    const int a     = je & 7;          // j-octet within row
    const int ihalf = je >> 3;         // which row of the i-pair
    const int j0    = 4 * a;

    __shared__ __align__(16) _Float16 Alds[16][72];   // 2.25 KB

    // ---- stage A tile (f32 -> f16): 16 bt-rows x 64 camps ----
    for (int e = tid; e < 16 * Cc; e += 256) {
        int c = e >> 4, m = e & 15;
        int bt = bt0 + m, b = bt / Tt, t = bt - b * Tt;
        Alds[m][c] = (_Float16)adstock[((size_t)b * Cc + c) * Dd + 1 + t];
    }
    __syncthreads();

    const f16x8 a0 = *reinterpret_cast<const f16x8*>(&Alds[je][grp * 8]);
    const f16x8 a1 = *reinterpret_cast<const f16x8*>(&Alds[je][32 + grp * 8]);

    // lane base into Bt; frag (qp,p,kh) at bp + (qp*64 + p*16)*64 + kh*32
    const _Float16* bp = Bt + ((size_t)(nq * 256 + je)) * Cc + grp * 8;
    const float* ep = emu_perm + nq * 256 + je;

    const float m3 = (a == 7) ? 0.0f : 1.0f;   // mask padded j=31 in den

    #pragma unroll
    for (int qp = 0; qp < 4; ++qp) {
        // ---- B frags + emu for this i-pair ----
        f16x8 Bf[8];
        #pragma unroll
        for (int u = 0; u < 8; ++u)
            Bf[u] = *reinterpret_cast<const f16x8*>(
                bp + (size_t)(qp * 64 + (u >> 1) * 16) * Cc + (u & 1) * 32);
        float emu[4];
        #pragma unroll
        for (int p = 0; p < 4; ++p) emu[p] = ep[qp * 64 + p * 16];

        // ---- 8 MFMAs -> acc[p] over 4 bt-rows ----
        f32x4 acc[4];
        #pragma unroll
        for (int p = 0; p < 4; ++p) {
            f32x4 z = {0.f, 0.f, 0.f, 0.f};
            f32x4 t0 = __builtin_amdgcn_mfma_f32_16x16x32_f16(a0, Bf[2 * p], z, 0, 0, 0);
            acc[p] = __builtin_amdgcn_mfma_f32_16x16x32_f16(a1, Bf[2 * p + 1], t0, 0, 0, 0);
        }

        // ---- epilogue ----
        const int iA = nq * 8 + 2 * qp;
        const int i_lane = iA + ihalf;
        const size_t obase = (size_t)(bt0 + grp * 4) * 1024 + (size_t)i_lane * 32 + j0;

        #pragma unroll
        for (int r = 0; r < 4; ++r) {
            float np[4];
            #pragma unroll
            for (int p = 0; p < 4; ++p) np[p] = __expf(acc[p][r]) * emu[p];

            // den: 8-lane reduce (same i) of np0+np1+np2+np3(masked)
            float s = np[0] + np[1] + fmaf(np[3], m3, np[2]);
            s = dpp_add<0xB1>(s);                      // quad xor1
            s = dpp_add<0x4E>(s);                      // quad xor2
            float t1 = dpp_mov<0x124>(s);              // row_ror:4  (src n-4)
            float t2 = dpp_mov<0x12C>(s);              // row_ror:12 (src n+4)
            // partner quad: a in 0..3 -> src n+4 (t2); a in 4..7 -> src n-4 (t1)
            s += (je & 4) ? t1 : t2;
            const float inv = __builtin_amdgcn_rcpf(1.0f + s);   // == Q_same

            const float sh0 = dpp_mov<0x111>(np[3]);   // lane je-1's np3 = num[j0-1]
            const float prev[4] = {sh0, np[0], np[1], np[2]};

            float v[4];
            #pragma unroll
            for (int p = 0; p < 4; ++p) {
                const int j = j0 + p;
                float x = (j < i_lane) ? np[p] * inv
                        : ((j == i_lane) ? inv : prev[p] * inv);
                v[p] = fmaxf(x, BASISF);
            }
            if (nq == 3 && qp == 3) {                  // absorbing row i=31
                const bool ab = (i_lane == SM1);
                v[0] = ab ? BASISF : v[0];
                v[1] = ab ? BASISF : v[1];
                v[2] = ab ? BASISF : v[2];
                v[3] = ab ? ((a == 7) ? (1.0f - SM1 * BASISF) : BASISF) : v[3];
            }
            f32x4 vv = {v[0], v[1], v[2], v[3]};
            *reinterpret_cast<f32x4*>(out + obase + (size_t)r * 1024) = vv;
        }
    }
}

// ---------------------------------------------------------------------------
// Fallback (no workspace): round-1 scalar kernel.
// ---------------------------------------------------------------------------
__global__ __launch_bounds__(256, 4)
void transition_fallback_kernel(const float* __restrict__ adstock,
                                const float* __restrict__ beta,
                                const float* __restrict__ mu,
                                float* __restrict__ out) {
    const int b  = blockIdx.x;
    const int t0 = blockIdx.y * 16;
    const int tid = threadIdx.x;

    __shared__ float adT[Cc][16];
    __shared__ float num_lds[8][964];

    for (int k = tid; k < Cc * 16; k += 256) {
        int c = k >> 4, tt = k & 15, t = t0 + tt;
        adT[c][tt] = (t < Tt) ? adstock[(size_t)b * (Cc * Dd) + c * Dd + 1 + t] : 0.0f;
    }
    __syncthreads();

    const int ij0 = tid * 4;
    const bool active = (ij0 < 964);
    float acc[16][4];
    #pragma unroll
    for (int tt = 0; tt < 16; ++tt) { acc[tt][0]=0;acc[tt][1]=0;acc[tt][2]=0;acc[tt][3]=0; }

    if (active) {
        for (int c = 0; c < Cc; ++c) {
            const float* bsrc = beta + (size_t)c * NIJ;
            float w0 = (ij0+0<NIJ)?bsrc[ij0+0]:0.f, w1 = (ij0+1<NIJ)?bsrc[ij0+1]:0.f;
            float w2 = (ij0+2<NIJ)?bsrc[ij0+2]:0.f, w3 = (ij0+3<NIJ)?bsrc[ij0+3]:0.f;
            #pragma unroll
            for (int tt = 0; tt < 16; ++tt) {
                float av = adT[c][tt];
                acc[tt][0] = fmaf(av, w0, acc[tt][0]);
                acc[tt][1] = fmaf(av, w1, acc[tt][1]);
                acc[tt][2] = fmaf(av, w2, acc[tt][2]);
                acc[tt][3] = fmaf(av, w3, acc[tt][3]);
            }
        }
    }
    float m0=0,m1=0,m2=0,m3=0;
    if (active) {
        m0 = (ij0+0<NIJ)?mu[ij0+0]:0.f; m1 = (ij0+1<NIJ)?mu[ij0+1]:0.f;
        m2 = (ij0+2<NIJ)?mu[ij0+2]:0.f; m3 = (ij0+3<NIJ)?mu[ij0+3]:0.f;
    }
    const int q8 = tid >> 5, irow = tid & 31;
    #pragma unroll
    for (int half = 0; half < 2; ++half) {
        if (active) {
            #pragma unroll
            for (int q = 0; q < 8; ++q) {
                const int tt = half * 8 + q;
                num_lds[q][ij0+0] = __expf(acc[tt][0] - m0);
                num_lds[q][ij0+1] = __expf(acc[tt][1] - m1);
                num_lds[q][ij0+2] = __expf(acc[tt][2] - m2);
                num_lds[q][ij0+3] = __expf(acc[tt][3] - m3);
            }
        }
        __syncthreads();
        const int t = t0 + half * 8 + q8;
        if (t < Tt) {
            float* op = out + (((size_t)b * Tt + t) * Ss + irow) * Ss;
            if (irow < SM1) {
                float row[SM1]; float den = 1.0f;
                #pragma unroll
                for (int j = 0; j < SM1; ++j) { row[j] = num_lds[q8][irow*SM1+j]; den += row[j]; }
                const float inv = 1.0f / den;
                #pragma unroll
                for (int j = 0; j < Ss; ++j) {
                    float vv = (j < irow) ? row[j]*inv : ((j == irow) ? inv
                              : (j-1 < SM1 ? row[j-1]*inv : 0.f));
                    op[j] = fmaxf(vv, BASISF);
                }
            } else {
                #pragma unroll
                for (int j = 0; j < Ss; ++j) op[j] = (j == SM1) ? (1.0f - SM1*BASISF) : BASISF;
            }
        }
        __syncthreads();
    }
}

// ---------------------------------------------------------------------------
extern "C" void kernel_launch(void* const* d_in, const int* in_sizes, int n_in,
                              void* d_out, int out_size, void* d_ws, size_t ws_size,
                              hipStream_t stream) {
    const float* adstock = (const float*)d_in[0];
    const float* mu      = (const float*)d_in[1];
    const float* beta    = (const float*)d_in[2];
    float* out = (float*)d_out;

    const size_t need = (size_t)1024 * Cc * sizeof(_Float16) + 1024 * sizeof(float);

    if (ws_size >= need) {
        _Float16* Bt = (_Float16*)d_ws;
        float* emu_perm = (float*)((char*)d_ws + (size_t)1024 * Cc * sizeof(_Float16));
        prep_kernel<<<(1024 * Cc) / 256, 256, 0, stream>>>(mu, beta, Bt, emu_perm);
        const int nblocks = (Bb * Tt) / 16;   // 2912
        transition_mfma_kernel<<<nblocks, 256, 0, stream>>>(adstock, Bt, emu_perm, out);
    } else {
        dim3 grid(Bb, (Tt + 15) / 16);
        transition_fallback_kernel<<<grid, 256, 0, stream>>>(adstock, beta, mu, out);
    }
}

// Round 8
// 44.219 us; speedup vs baseline: 1.5103x; 1.5103x over previous
//
#include <hip/hip_runtime.h>
#include <cstdint>
#include <cstddef>

#define Bb 128
#define Cc 64
#define Dd 365
#define Tt 364
#define Ss 32
#define SM1 31
#define NIJ 961
#define BASISF 1e-10f
#define NTILES 1456        // 46592 bt / 32 per tile
#define NBLK 256           // persistent blocks, 1 per CU

typedef _Float16 f16x8 __attribute__((ext_vector_type(8)));
typedef _Float16 f16x4 __attribute__((ext_vector_type(4)));
typedef float f32x4 __attribute__((ext_vector_type(4)));

// ---------------------------------------------------------------------------
// Prep: B2 (f16, 65536 elems = 128 KB) in the LDS-friendly layout
//   f16 index = ((c>>3)*1024 + m)*8 + (c&7)
// i.e. for each 8-c slice (kh*4+grp), 1024 columns x 16B chunks. Column
// m <-> (i,j) mapping (R7, HW-verified):
//   nq=m>>8, rem=m&255, qp=rem>>6, p=(rem>>4)&3, v=rem&15;
//   i = nq*8 + qp*2 + (v>>3);  j = 4*(v&7) + p.
// emu_perm[1024] = exp(-mu) in the same column permutation.
// ---------------------------------------------------------------------------
__global__ void prep_kernel(const float* __restrict__ mu,
                            const float* __restrict__ beta,
                            _Float16* __restrict__ B2,
                            float* __restrict__ emu_perm) {
    int idx = blockIdx.x * blockDim.x + threadIdx.x;   // 0 .. 65535
    int m = idx >> 6, c = idx & 63;
    int nq = m >> 8, rem = m & 255, qp = rem >> 6, p = (rem >> 4) & 3, v = rem & 15;
    int i = nq * 8 + qp * 2 + (v >> 3);
    int j = 4 * (v & 7) + p;
    float val = (i < SM1 && j < SM1) ? beta[c * NIJ + i * SM1 + j] : 0.0f;
    B2[((size_t)(c >> 3) * 1024 + m) * 8 + (c & 7)] = (_Float16)val;
    if (idx < 1024) {
        int m2 = idx;
        int nq2 = m2 >> 8, rem2 = m2 & 255, qp2 = rem2 >> 6;
        int p2 = (rem2 >> 4) & 3, v2 = rem2 & 15;
        int i2 = nq2 * 8 + qp2 * 2 + (v2 >> 3);
        int j2 = 4 * (v2 & 7) + p2;
        emu_perm[m2] = (i2 < SM1 && j2 < SM1) ? __expf(-mu[i2 * SM1 + j2]) : 1.0f;
    }
}

// ---- DPP helpers (pure VALU cross-lane; no DS pipe) ----
template <int CTRL>
__device__ __forceinline__ float dpp_mov(float x) {
    union { float f; int i; } u, v;
    u.f = x;
    v.i = __builtin_amdgcn_update_dpp(0, u.i, CTRL, 0xf, 0xf, true);
    return v.f;
}
template <int CTRL>
__device__ __forceinline__ float dpp_add(float s) { return s + dpp_mov<CTRL>(s); }
// quad_perm xor1 = 0xB1 ; xor2 = 0x4E ; row_ror:4 = 0x124 ; row_ror:12 = 0x12C
// row_shr:1 = 0x111.  Cross-quad select HW-verified in round 7.

// ---------------------------------------------------------------------------
// Persistent kernel: 256 blocks x 512 threads (8 waves), 1 block/CU.
// Prologue: copy B2 (128 KB) + nothing else global for B ever again.
// Loop over ~5.7 tiles of 32 bt: prefetch next A (regs), compute current
// (LDS B-frags + MFMA + in-register epilogue + dwordx4 stores), ds_write
// next A into the alternate buffer, one barrier.
// ---------------------------------------------------------------------------
__global__ __launch_bounds__(512, 2)
void transition_persist_kernel(const float* __restrict__ adstock,
                               const _Float16* __restrict__ B2,
                               const float* __restrict__ emu_perm,
                               float* __restrict__ out)
{
    const int tid  = threadIdx.x;
    const int lane = tid & 63;
    const int w    = tid >> 6;         // wave 0..7
    const int je   = lane & 15;
    const int grp  = lane >> 4;
    const int mh   = w >> 2;           // bt half (16 rows)
    const int nq   = w & 3;            // column quarter = i-rows nq*8..+7
    const int a     = je & 7;
    const int ihalf = je >> 3;
    const int j0    = 4 * a;

    __shared__ _Float16 Blds[65536];                  // 128 KB
    __shared__ __align__(16) _Float16 Alds[2][32][72]; // 9.2 KB (144 B rows)

    // ---- B: global -> LDS, linear copy (16 sweeps x 16B per thread) ----
    #pragma unroll
    for (int s = 0; s < 16; ++s) {
        const int o8 = s * 4096 + tid * 8;            // f16 units
        *reinterpret_cast<f16x8*>(&Blds[o8]) =
            *reinterpret_cast<const f16x8*>(B2 + o8);
    }

    // ---- emu -> 16 registers per lane ----
    float emu[4][4];
    #pragma unroll
    for (int qp = 0; qp < 4; ++qp)
        #pragma unroll
        for (int p = 0; p < 4; ++p)
            emu[qp][p] = emu_perm[nq * 256 + qp * 64 + p * 16 + je];

    const float m3 = (a == 7) ? 0.0f : 1.0f;          // mask padded j=31

    // ---- tile range for this block ----
    const int tb = (NTILES * blockIdx.x) / NBLK;
    const int te = (NTILES * (blockIdx.x + 1)) / NBLK;

    // ---- A staging indices (per thread) ----
    const int m_s = tid >> 4;          // 0..31 bt-row
    const int c0  = (tid & 15) * 4;    // 4 consecutive camps

    // prologue: stage A(tb) into buf 0
    {
        const int bt = tb * 32 + m_s;
        const int b = bt / Tt, t = bt - b * Tt;
        float av0 = adstock[((size_t)b * Cc + c0 + 0) * Dd + 1 + t];
        float av1 = adstock[((size_t)b * Cc + c0 + 1) * Dd + 1 + t];
        float av2 = adstock[((size_t)b * Cc + c0 + 2) * Dd + 1 + t];
        float av3 = adstock[((size_t)b * Cc + c0 + 3) * Dd + 1 + t];
        f16x4 pk = {(_Float16)av0, (_Float16)av1, (_Float16)av2, (_Float16)av3};
        *reinterpret_cast<f16x4*>(&Alds[0][m_s][c0]) = pk;
    }
    __syncthreads();

    for (int tile = tb; tile < te; ++tile) {
        const int cur = (tile - tb) & 1, nxt = cur ^ 1;

        // ---- prefetch next tile's A into registers ----
        float av0, av1, av2, av3;
        const bool have = (tile + 1 < te);
        if (have) {
            const int bt = (tile + 1) * 32 + m_s;
            const int b = bt / Tt, t = bt - b * Tt;
            av0 = adstock[((size_t)b * Cc + c0 + 0) * Dd + 1 + t];
            av1 = adstock[((size_t)b * Cc + c0 + 1) * Dd + 1 + t];
            av2 = adstock[((size_t)b * Cc + c0 + 2) * Dd + 1 + t];
            av3 = adstock[((size_t)b * Cc + c0 + 3) * Dd + 1 + t];
        }

        // ---- compute current tile ----
        const f16x8 a0 = *reinterpret_cast<const f16x8*>(&Alds[cur][mh * 16 + je][grp * 8]);
        const f16x8 a1 = *reinterpret_cast<const f16x8*>(&Alds[cur][mh * 16 + je][32 + grp * 8]);

        const int bt0 = tile * 32 + mh * 16;

        #pragma unroll
        for (int qp = 0; qp < 4; ++qp) {
            // B frags from LDS: f16 idx = ((kh*4+grp)*1024 + col)*8
            const int colb = nq * 256 + qp * 64 + je;
            f16x8 Bf[8];
            #pragma unroll
            for (int p = 0; p < 4; ++p) {
                Bf[2 * p]     = *reinterpret_cast<const f16x8*>(
                    &Blds[((0 * 4 + grp) * 1024 + colb + p * 16) * 8]);
                Bf[2 * p + 1] = *reinterpret_cast<const f16x8*>(
                    &Blds[((1 * 4 + grp) * 1024 + colb + p * 16) * 8]);
            }

            f32x4 acc[4];
            #pragma unroll
            for (int p = 0; p < 4; ++p) {
                f32x4 z = {0.f, 0.f, 0.f, 0.f};
                f32x4 t0 = __builtin_amdgcn_mfma_f32_16x16x32_f16(a0, Bf[2 * p], z, 0, 0, 0);
                acc[p] = __builtin_amdgcn_mfma_f32_16x16x32_f16(a1, Bf[2 * p + 1], t0, 0, 0, 0);
            }

            const int i_lane = nq * 8 + 2 * qp + ihalf;
            const size_t obase = (size_t)(bt0 + grp * 4) * 1024
                               + (size_t)i_lane * 32 + j0;

            #pragma unroll
            for (int r = 0; r < 4; ++r) {
                float np[4];
                #pragma unroll
                for (int p = 0; p < 4; ++p) np[p] = __expf(acc[p][r]) * emu[qp][p];

                float s = np[0] + np[1] + fmaf(np[3], m3, np[2]);
                s = dpp_add<0xB1>(s);                  // quad xor1
                s = dpp_add<0x4E>(s);                  // quad xor2
                float t1 = dpp_mov<0x124>(s);          // row_ror:4
                float t2 = dpp_mov<0x12C>(s);          // row_ror:12
                s += (je & 4) ? t1 : t2;               // partner quad (R7-verified)
                const float inv = __builtin_amdgcn_rcpf(1.0f + s);

                const float sh0 = dpp_mov<0x111>(np[3]);
                const float prev[4] = {sh0, np[0], np[1], np[2]};

                float v[4];
                #pragma unroll
                for (int p = 0; p < 4; ++p) {
                    const int j = j0 + p;
                    float x = (j < i_lane) ? np[p] * inv
                            : ((j == i_lane) ? inv : prev[p] * inv);
                    v[p] = fmaxf(x, BASISF);
                }
                if (nq == 3 && qp == 3) {              // absorbing row i=31
                    const bool ab = (i_lane == SM1);
                    v[0] = ab ? BASISF : v[0];
                    v[1] = ab ? BASISF : v[1];
                    v[2] = ab ? BASISF : v[2];
                    v[3] = ab ? ((a == 7) ? (1.0f - SM1 * BASISF) : BASISF) : v[3];
                }
                f32x4 vv = {v[0], v[1], v[2], v[3]};
                *reinterpret_cast<f32x4*>(out + obase + (size_t)r * 1024) = vv;
            }
        }

        // ---- write next tile's A, single barrier per tile ----
        if (have) {
            f16x4 pk = {(_Float16)av0, (_Float16)av1, (_Float16)av2, (_Float16)av3};
            *reinterpret_cast<f16x4*>(&Alds[nxt][m_s][c0]) = pk;
        }
        __syncthreads();
    }
}

// ---------------------------------------------------------------------------
// Fallback (no workspace): round-1 scalar kernel.
// ---------------------------------------------------------------------------
__global__ __launch_bounds__(256, 4)
void transition_fallback_kernel(const float* __restrict__ adstock,
                                const float* __restrict__ beta,
                                const float* __restrict__ mu,
                                float* __restrict__ out) {
    const int b  = blockIdx.x;
    const int t0 = blockIdx.y * 16;
    const int tid = threadIdx.x;

    __shared__ float adT[Cc][16];
    __shared__ float num_lds[8][964];

    for (int k = tid; k < Cc * 16; k += 256) {
        int c = k >> 4, tt = k & 15, t = t0 + tt;
        adT[c][tt] = (t < Tt) ? adstock[(size_t)b * (Cc * Dd) + c * Dd + 1 + t] : 0.0f;
    }
    __syncthreads();

    const int ij0 = tid * 4;
    const bool active = (ij0 < 964);
    float acc[16][4];
    #pragma unroll
    for (int tt = 0; tt < 16; ++tt) { acc[tt][0]=0;acc[tt][1]=0;acc[tt][2]=0;acc[tt][3]=0; }

    if (active) {
        for (int c = 0; c < Cc; ++c) {
            const float* bsrc = beta + (size_t)c * NIJ;
            float w0 = (ij0+0<NIJ)?bsrc[ij0+0]:0.f, w1 = (ij0+1<NIJ)?bsrc[ij0+1]:0.f;
            float w2 = (ij0+2<NIJ)?bsrc[ij0+2]:0.f, w3 = (ij0+3<NIJ)?bsrc[ij0+3]:0.f;
            #pragma unroll
            for (int tt = 0; tt < 16; ++tt) {
                float av = adT[c][tt];
                acc[tt][0] = fmaf(av, w0, acc[tt][0]);
                acc[tt][1] = fmaf(av, w1, acc[tt][1]);
                acc[tt][2] = fmaf(av, w2, acc[tt][2]);
                acc[tt][3] = fmaf(av, w3, acc[tt][3]);
            }
        }
    }
    float m0=0,m1=0,m2=0,m3=0;
    if (active) {
        m0 = (ij0+0<NIJ)?mu[ij0+0]:0.f; m1 = (ij0+1<NIJ)?mu[ij0+1]:0.f;
        m2 = (ij0+2<NIJ)?mu[ij0+2]:0.f; m3 = (ij0+3<NIJ)?mu[ij0+3]:0.f;
    }
    const int q8 = tid >> 5, irow = tid & 31;
    #pragma unroll
    for (int half = 0; half < 2; ++half) {
        if (active) {
            #pragma unroll
            for (int q = 0; q < 8; ++q) {
                const int tt = half * 8 + q;
                num_lds[q][ij0+0] = __expf(acc[tt][0] - m0);
                num_lds[q][ij0+1] = __expf(acc[tt][1] - m1);
                num_lds[q][ij0+2] = __expf(acc[tt][2] - m2);
                num_lds[q][ij0+3] = __expf(acc[tt][3] - m3);
            }
        }
        __syncthreads();
        const int t = t0 + half * 8 + q8;
        if (t < Tt) {
            float* op = out + (((size_t)b * Tt + t) * Ss + irow) * Ss;
            if (irow < SM1) {
                float row[SM1]; float den = 1.0f;
                #pragma unroll
                for (int j = 0; j < SM1; ++j) { row[j] = num_lds[q8][irow*SM1+j]; den += row[j]; }
                const float inv = 1.0f / den;
                #pragma unroll
                for (int j = 0; j < Ss; ++j) {
                    float vv = (j < irow) ? row[j]*inv : ((j == irow) ? inv
                              : (j-1 < SM1 ? row[j-1]*inv : 0.f));
                    op[j] = fmaxf(vv, BASISF);
                }
            } else {
                #pragma unroll
                for (int j = 0; j < Ss; ++j) op[j] = (j == SM1) ? (1.0f - SM1*BASISF) : BASISF;
            }
        }
        __syncthreads();
    }
}

// ---------------------------------------------------------------------------
extern "C" void kernel_launch(void* const* d_in, const int* in_sizes, int n_in,
                              void* d_out, int out_size, void* d_ws, size_t ws_size,
                              hipStream_t stream) {
    const float* adstock = (const float*)d_in[0];
    const float* mu      = (const float*)d_in[1];
    const float* beta    = (const float*)d_in[2];
    float* out = (float*)d_out;

    const size_t need = (size_t)65536 * sizeof(_Float16) + 1024 * sizeof(float);

    if (ws_size >= need) {
        _Float16* B2 = (_Float16*)d_ws;
        float* emu_perm = (float*)((char*)d_ws + (size_t)65536 * sizeof(_Float16));
        prep_kernel<<<(1024 * Cc) / 256, 256, 0, stream>>>(mu, beta, B2, emu_perm);
        transition_persist_kernel<<<NBLK, 512, 0, stream>>>(adstock, B2, emu_perm, out);
    } else {
        dim3 grid(Bb, (Tt + 15) / 16);
        transition_fallback_kernel<<<grid, 256, 0, stream>>>(adstock, beta, mu, out);
    }
}

// Round 10
// 43.565 us; speedup vs baseline: 1.5330x; 1.0150x over previous
//
#include <hip/hip_runtime.h>
#include <cstdint>
#include <cstddef>

#define Bb 128
#define Cc 64
#define Dd 365
#define Tt 364
#define Ss 32
#define SM1 31
#define NIJ 961
#define BASISF 1e-10f
#define NTILES 728         // 46592 bt / 64 per tile
#define NBLK 256           // persistent blocks, 1 per CU

typedef _Float16 f16x8 __attribute__((ext_vector_type(8)));
typedef _Float16 f16x4 __attribute__((ext_vector_type(4)));
typedef float f32x4 __attribute__((ext_vector_type(4)));

// ---------------------------------------------------------------------------
// Prep: B2 (f16, 65536 = 128 KB) in the LDS layout
//   f16 index = ((c>>3)*1024 + m)*8 + (c&7)
// Column m <-> (i,j) mapping (HW-verified R7/R8):
//   nq=m>>8, rem=m&255, qp=rem>>6, p=(rem>>4)&3, v=rem&15;
//   i = nq*8 + qp*2 + (v>>3);  j = 4*(v&7) + p.
// emu_perm[1024] = exp(-mu) in the same column permutation.
// ---------------------------------------------------------------------------
__global__ void prep_kernel(const float* __restrict__ mu,
                            const float* __restrict__ beta,
                            _Float16* __restrict__ B2,
                            float* __restrict__ emu_perm) {
    int idx = blockIdx.x * blockDim.x + threadIdx.x;   // 0 .. 65535
    int m = idx >> 6, c = idx & 63;
    int nq = m >> 8, rem = m & 255, qp = rem >> 6, p = (rem >> 4) & 3, v = rem & 15;
    int i = nq * 8 + qp * 2 + (v >> 3);
    int j = 4 * (v & 7) + p;
    float val = (i < SM1 && j < SM1) ? beta[c * NIJ + i * SM1 + j] : 0.0f;
    B2[((size_t)(c >> 3) * 1024 + m) * 8 + (c & 7)] = (_Float16)val;
    if (idx < 1024) {
        int m2 = idx;
        int nq2 = m2 >> 8, rem2 = m2 & 255, qp2 = rem2 >> 6;
        int p2 = (rem2 >> 4) & 3, v2 = rem2 & 15;
        int i2 = nq2 * 8 + qp2 * 2 + (v2 >> 3);
        int j2 = 4 * (v2 & 7) + p2;
        emu_perm[m2] = (i2 < SM1 && j2 < SM1) ? __expf(-mu[i2 * SM1 + j2]) : 1.0f;
    }
}

// ---- DPP helpers (pure VALU cross-lane; no DS pipe) ----
template <int CTRL>
__device__ __forceinline__ float dpp_mov(float x) {
    union { float f; int i; } u, v;
    u.f = x;
    v.i = __builtin_amdgcn_update_dpp(0, u.i, CTRL, 0xf, 0xf, true);
    return v.f;
}
template <int CTRL>
__device__ __forceinline__ float dpp_add(float s) { return s + dpp_mov<CTRL>(s); }
// quad_perm xor1 = 0xB1 ; xor2 = 0x4E ; row_ror:4 = 0x124 ; row_ror:12 = 0x12C
// row_shr:1 = 0x111.  Cross-quad select HW-verified in round 7.

// ---------------------------------------------------------------------------
// Persistent kernel: 256 blocks x 1024 threads (16 waves), 1 block/CU.
// Prologue: linear coalesced copy of B2 (128 KB) into LDS; emu -> 16 regs.
// Per 64-bt tile (two-barrier, provably race-free single A buffer):
//   barrier; ds_write A(tile) from regs; barrier;
//   prefetch A(tile+1) -> regs;  compute (LDS B frags + MFMA + DPP epilogue
//   + dwordx4 stores).
// ---------------------------------------------------------------------------
__global__ __launch_bounds__(1024, 1)
void transition_persist_kernel(const float* __restrict__ adstock,
                               const _Float16* __restrict__ B2,
                               const float* __restrict__ emu_perm,
                               float* __restrict__ out)
{
    const int tid  = threadIdx.x;
    const int lane = tid & 63;
    const int w    = tid >> 6;         // wave 0..15
    const int je   = lane & 15;
    const int grp  = lane >> 4;
    const int mh   = w >> 2;           // bt quarter (16 rows each)
    const int nq   = w & 3;            // column quarter = i-rows nq*8..+7
    const int a     = je & 7;
    const int ihalf = je >> 3;
    const int j0    = 4 * a;

    __shared__ _Float16 Blds[65536];                // 128 KB
    __shared__ __align__(16) _Float16 Alds[64][72]; // 9 KB (144 B rows)

    // ---- B: global -> LDS, linear coalesced copy (8 sweeps x 16 B) ----
    #pragma unroll
    for (int s = 0; s < 8; ++s) {
        const int o8 = s * 8192 + tid * 8;          // f16 units
        *reinterpret_cast<f16x8*>(&Blds[o8]) =
            *reinterpret_cast<const f16x8*>(B2 + o8);
    }

    // ---- emu -> 16 registers per lane ----
    float emu[4][4];
    #pragma unroll
    for (int qp = 0; qp < 4; ++qp)
        #pragma unroll
        for (int p = 0; p < 4; ++p)
            emu[qp][p] = emu_perm[nq * 256 + qp * 64 + p * 16 + je];

    const float m3 = (a == 7) ? 0.0f : 1.0f;        // mask padded j=31

    // ---- tile range for this block ----
    const int tb = (NTILES * blockIdx.x) / NBLK;
    const int te = (NTILES * (blockIdx.x + 1)) / NBLK;

    // ---- A staging indices (per thread): 64 rows x 16 c-groups ----
    const int m_s = tid >> 4;          // 0..63 bt-row within tile
    const int c0  = (tid & 15) * 4;    // 4 consecutive camps

    // prefetch A(tb) into registers
    float av0, av1, av2, av3;
    {
        const int bt = tb * 64 + m_s;
        const int b = bt / Tt, t = bt - b * Tt;
        av0 = adstock[((size_t)b * Cc + c0 + 0) * Dd + 1 + t];
        av1 = adstock[((size_t)b * Cc + c0 + 1) * Dd + 1 + t];
        av2 = adstock[((size_t)b * Cc + c0 + 2) * Dd + 1 + t];
        av3 = adstock[((size_t)b * Cc + c0 + 3) * Dd + 1 + t];
    }

    for (int tile = tb; tile < te; ++tile) {
        // ---- phase 1: publish A(tile); barriers isolate reads from writes ----
        __syncthreads();   // all prior-tile reads of Alds complete
        {
            f16x4 pk = {(_Float16)av0, (_Float16)av1, (_Float16)av2, (_Float16)av3};
            *reinterpret_cast<f16x4*>(&Alds[m_s][c0]) = pk;
        }
        __syncthreads();   // A(tile) visible to all waves (Blds ready on 1st iter)

        // ---- prefetch A(tile+1) into regs (latency hidden under compute) ----
        if (tile + 1 < te) {
            const int bt = (tile + 1) * 64 + m_s;
            const int b = bt / Tt, t = bt - b * Tt;
            av0 = adstock[((size_t)b * Cc + c0 + 0) * Dd + 1 + t];
            av1 = adstock[((size_t)b * Cc + c0 + 1) * Dd + 1 + t];
            av2 = adstock[((size_t)b * Cc + c0 + 2) * Dd + 1 + t];
            av3 = adstock[((size_t)b * Cc + c0 + 3) * Dd + 1 + t];
        }

        // ---- compute current tile ----
        const f16x8 a0 = *reinterpret_cast<const f16x8*>(&Alds[mh * 16 + je][grp * 8]);
        const f16x8 a1 = *reinterpret_cast<const f16x8*>(&Alds[mh * 16 + je][32 + grp * 8]);

        const int bt0 = tile * 64 + mh * 16;

        #pragma unroll
        for (int qp = 0; qp < 4; ++qp) {
            // B frags from LDS: f16 idx = ((kh*4+grp)*1024 + col)*8
            const int colb = nq * 256 + qp * 64 + je;
            f16x8 Bf[8];
            #pragma unroll
            for (int p = 0; p < 4; ++p) {
                Bf[2 * p]     = *reinterpret_cast<const f16x8*>(
                    &Blds[((0 * 4 + grp) * 1024 + colb + p * 16) * 8]);
                Bf[2 * p + 1] = *reinterpret_cast<const f16x8*>(
                    &Blds[((1 * 4 + grp) * 1024 + colb + p * 16) * 8]);
            }

            f32x4 acc[4];
            #pragma unroll
            for (int p = 0; p < 4; ++p) {
                f32x4 z = {0.f, 0.f, 0.f, 0.f};
                f32x4 t0 = __builtin_amdgcn_mfma_f32_16x16x32_f16(a0, Bf[2 * p], z, 0, 0, 0);
                acc[p] = __builtin_amdgcn_mfma_f32_16x16x32_f16(a1, Bf[2 * p + 1], t0, 0, 0, 0);
            }

            const int i_lane = nq * 8 + 2 * qp + ihalf;
            const size_t obase = (size_t)(bt0 + grp * 4) * 1024
                               + (size_t)i_lane * 32 + j0;

            #pragma unroll
            for (int r = 0; r < 4; ++r) {
                float np[4];
                #pragma unroll
                for (int p = 0; p < 4; ++p) np[p] = __expf(acc[p][r]) * emu[qp][p];

                float s = np[0] + np[1] + fmaf(np[3], m3, np[2]);
                s = dpp_add<0xB1>(s);                  // quad xor1
                s = dpp_add<0x4E>(s);                  // quad xor2
                float t1 = dpp_mov<0x124>(s);          // row_ror:4
                float t2 = dpp_mov<0x12C>(s);          // row_ror:12
                s += (je & 4) ? t1 : t2;               // partner quad (R7-verified)
                const float inv = __builtin_amdgcn_rcpf(1.0f + s);

                const float sh0 = dpp_mov<0x111>(np[3]);
                const float prev[4] = {sh0, np[0], np[1], np[2]};

                float v[4];
                #pragma unroll
                for (int p = 0; p < 4; ++p) {
                    const int j = j0 + p;
                    float x = (j < i_lane) ? np[p] * inv
                            : ((j == i_lane) ? inv : prev[p] * inv);
                    v[p] = fmaxf(x, BASISF);
                }
                if (nq == 3 && qp == 3) {              // absorbing row i=31
                    const bool ab = (i_lane == SM1);
                    v[0] = ab ? BASISF : v[0];
                    v[1] = ab ? BASISF : v[1];
                    v[2] = ab ? BASISF : v[2];
                    v[3] = ab ? ((a == 7) ? (1.0f - SM1 * BASISF) : BASISF) : v[3];
                }
                f32x4 vv = {v[0], v[1], v[2], v[3]};
                *reinterpret_cast<f32x4*>(out + obase + (size_t)r * 1024) = vv;
            }
        }
    }
}

// ---------------------------------------------------------------------------
// Fallback (no workspace): round-1 scalar kernel.
// ---------------------------------------------------------------------------
__global__ __launch_bounds__(256, 4)
void transition_fallback_kernel(const float* __restrict__ adstock,
                                const float* __restrict__ beta,
                                const float* __restrict__ mu,
                                float* __restrict__ out) {
    const int b  = blockIdx.x;
    const int t0 = blockIdx.y * 16;
    const int tid = threadIdx.x;

    __shared__ float adT[Cc][16];
    __shared__ float num_lds[8][964];

    for (int k = tid; k < Cc * 16; k += 256) {
        int c = k >> 4, tt = k & 15, t = t0 + tt;
        adT[c][tt] = (t < Tt) ? adstock[(size_t)b * (Cc * Dd) + c * Dd + 1 + t] : 0.0f;
    }
    __syncthreads();

    const int ij0 = tid * 4;
    const bool active = (ij0 < 964);
    float acc[16][4];
    #pragma unroll
    for (int tt = 0; tt < 16; ++tt) { acc[tt][0]=0;acc[tt][1]=0;acc[tt][2]=0;acc[tt][3]=0; }

    if (active) {
        for (int c = 0; c < Cc; ++c) {
            const float* bsrc = beta + (size_t)c * NIJ;
            float w0 = (ij0+0<NIJ)?bsrc[ij0+0]:0.f, w1 = (ij0+1<NIJ)?bsrc[ij0+1]:0.f;
            float w2 = (ij0+2<NIJ)?bsrc[ij0+2]:0.f, w3 = (ij0+3<NIJ)?bsrc[ij0+3]:0.f;
            #pragma unroll
            for (int tt = 0; tt < 16; ++tt) {
                float av = adT[c][tt];
                acc[tt][0] = fmaf(av, w0, acc[tt][0]);
                acc[tt][1] = fmaf(av, w1, acc[tt][1]);
                acc[tt][2] = fmaf(av, w2, acc[tt][2]);
                acc[tt][3] = fmaf(av, w3, acc[tt][3]);
            }
        }
    }
    float m0=0,m1=0,m2=0,m3=0;
    if (active) {
        m0 = (ij0+0<NIJ)?mu[ij0+0]:0.f; m1 = (ij0+1<NIJ)?mu[ij0+1]:0.f;
        m2 = (ij0+2<NIJ)?mu[ij0+2]:0.f; m3 = (ij0+3<NIJ)?mu[ij0+3]:0.f;
    }
    const int q8 = tid >> 5, irow = tid & 31;
    #pragma unroll
    for (int half = 0; half < 2; ++half) {
        if (active) {
            #pragma unroll
            for (int q = 0; q < 8; ++q) {
                const int tt = half * 8 + q;
                num_lds[q][ij0+0] = __expf(acc[tt][0] - m0);
                num_lds[q][ij0+1] = __expf(acc[tt][1] - m1);
                num_lds[q][ij0+2] = __expf(acc[tt][2] - m2);
                num_lds[q][ij0+3] = __expf(acc[tt][3] - m3);
            }
        }
        __syncthreads();
        const int t = t0 + half * 8 + q8;
        if (t < Tt) {
            float* op = out + (((size_t)b * Tt + t) * Ss + irow) * Ss;
            if (irow < SM1) {
                float row[SM1]; float den = 1.0f;
                #pragma unroll
                for (int j = 0; j < SM1; ++j) { row[j] = num_lds[q8][irow*SM1+j]; den += row[j]; }
                const float inv = 1.0f / den;
                #pragma unroll
                for (int j = 0; j < Ss; ++j) {
                    float vv = (j < irow) ? row[j]*inv : ((j == irow) ? inv
                              : (j-1 < SM1 ? row[j-1]*inv : 0.f));
                    op[j] = fmaxf(vv, BASISF);
                }
            } else {
                #pragma unroll
                for (int j = 0; j < Ss; ++j) op[j] = (j == SM1) ? (1.0f - SM1*BASISF) : BASISF;
            }
        }
        __syncthreads();
    }
}

// ---------------------------------------------------------------------------
extern "C" void kernel_launch(void* const* d_in, const int* in_sizes, int n_in,
                              void* d_out, int out_size, void* d_ws, size_t ws_size,
                              hipStream_t stream) {
    const float* adstock = (const float*)d_in[0];
    const float* mu      = (const float*)d_in[1];
    const float* beta    = (const float*)d_in[2];
    float* out = (float*)d_out;

    const size_t need = (size_t)65536 * sizeof(_Float16) + 1024 * sizeof(float);

    if (ws_size >= need) {
        _Float16* B2 = (_Float16*)d_ws;
        float* emu_perm = (float*)((char*)d_ws + (size_t)65536 * sizeof(_Float16));
        prep_kernel<<<(1024 * Cc) / 256, 256, 0, stream>>>(mu, beta, B2, emu_perm);
        transition_persist_kernel<<<NBLK, 1024, 0, stream>>>(adstock, B2, emu_perm, out);
    } else {
        dim3 grid(Bb, (Tt + 15) / 16);
        transition_fallback_kernel<<<grid, 256, 0, stream>>>(adstock, beta, mu, out);
    }
}